// Round 19
// baseline (136.722 us; speedup 1.0000x reference)
//
#include <hip/hip_runtime.h>

// PerceptronSP: 8000 independent per-pixel MLPs sharing input x.
//   h1 = leaky(x @ W1[p] + b1[p]); h2 = leaky(h1 @ W2[p] + b2[p]);
//   y[:,p] = h2 @ W3[p] + b3[p].  ~650 MB streamed once.
//
// R19: PERSISTENT blocks (grid 2000, 4 pixels each) with a cross-pixel
// software pipeline: pixel p's tail stages pixel p+1's W1 t0/t1 (and issues
// its small reg loads BETWEEN them in the vmcnt FIFO, so the next body's
// standard vmcnt(4) retires {regs,t0'} exactly). Layer-3 runs with 8 KB in
// flight; only the last pixel drains. x^T staged once BEFORE any DMA.
// Buffer parity alternates per pixel (odd stage count) via macro args.
// Consume/stage/layout macros identical to R14 (verified).

constexpr int DIM_IN = 25;
constexpr int H      = 128;
constexpr int P      = 8000;
constexpr int BS     = 32;
constexpr int NPIX   = 4;
constexpr int GRID   = P / NPIX;   // 2000
constexpr float NEG  = 0.01f;

typedef short  short4v __attribute__((ext_vector_type(4)));
typedef short  short8v __attribute__((ext_vector_type(8)));
typedef float  f32x16  __attribute__((ext_vector_type(16)));

__device__ __forceinline__ float leaky(float v) { return v >= 0.f ? v : NEG * v; }

__device__ __forceinline__ short bf_rne(float f) {
    unsigned u = __builtin_bit_cast(unsigned, f);
    return (short)((u + 0x7fffu + ((u >> 16) & 1u)) >> 16);
}
__device__ __forceinline__ short bf_rna(float f) {
    unsigned u = __builtin_bit_cast(unsigned, f);
    return (short)((u + 0x8000u) >> 16);
}

// ---- 4KB tile staging via global_load_lds (verified R7+), pointer-param ----
// W1 tile T8: rows [8*T8,+8) x 128 cols; buf [8][128] f32.
#define STAGE_W1P(BUF, T8, W1Q) {                                              \
    const float* g_ = (W1Q) + (size_t)(8 * (T8)) * H + (t << 2);               \
    float* d_ = &w12t[BUF][0];                                                 \
    _Pragma("unroll")                                                          \
    for (int i_ = 0; i_ < 4; ++i_)                                             \
        __builtin_amdgcn_global_load_lds(                                      \
            (const __attribute__((address_space(1))) unsigned*)(g_ + i_ * 256),\
            (__attribute__((address_space(3))) unsigned*)(d_ + i_ * 256),      \
            16, 0, 0); }

// W2 tile: rows [16*KT,+16) x cols [64*HF,+64); buf [16][64] f32.
#define STAGE_TP(BUF, KT, HF, W2Q) {                                           \
    const float* g_ = (W2Q) + (size_t)(16 * (KT) + (t >> 4)) * H               \
                      + 64 * (HF) + ((t & 15) << 2);                           \
    float* d_ = &w12t[BUF][0];                                                 \
    _Pragma("unroll")                                                          \
    for (int i_ = 0; i_ < 4; ++i_)                                             \
        __builtin_amdgcn_global_load_lds(                                      \
            (const __attribute__((address_space(1))) unsigned*)(g_ + (size_t)i_ * 4 * H), \
            (__attribute__((address_space(3))) unsigned*)(d_ + i_ * 256),      \
            16, 0, 0); }

// layer-1 consume of one W1 tile (8 rows) from LDS.
#define L1_CONSUME(BUF, T8) {                                                  \
    _Pragma("unroll")                                                          \
    for (int dd_ = 0; dd_ < 8; ++dd_) {                                        \
        const int d_ = 8 * (T8) + dd_;                                         \
        const float4 a0_ = *reinterpret_cast<const float4*>(&sxT[d_][r0]);     \
        const float4 a1_ = *reinterpret_cast<const float4*>(&sxT[d_][r0 + 4]); \
        const float4 wl_ = *reinterpret_cast<const float4*>(&w12t[BUF][dd_ * H + c0]); \
        const float4 wh_ = *reinterpret_cast<const float4*>(&w12t[BUF][dd_ * H + 64 + c0]); \
        const float av_[8] = {a0_.x, a0_.y, a0_.z, a0_.w, a1_.x, a1_.y, a1_.z, a1_.w}; \
        const float wv_[8] = {wl_.x, wl_.y, wl_.z, wl_.w, wh_.x, wh_.y, wh_.z, wh_.w}; \
        _Pragma("unroll")                                                      \
        for (int i_ = 0; i_ < 8; ++i_)                                         \
            _Pragma("unroll")                                                  \
            for (int c_ = 0; c_ < 8; ++c_)                                     \
                aL1[i_][c_] += av_[i_] * wv_[c_];                              \
    } }

// layer-2 consume: one [16k x 64n] tile = one K=16 step of 32x32x16 MFMA.
#define CONSUME_T(BUF, KT, HF) {                                               \
    const int ao_ = lo * 256 + 32 * (KT) + 16 * hi;                            \
    const short8v a_ = *reinterpret_cast<const short8v*>(                      \
        (const char*)h1b + (ao_ ^ ((lo & 7) << 4)));                           \
    const float* tb_ = &w12t[BUF][hi * 512 + lo];                              \
    _Pragma("unroll")                                                          \
    for (int n2_ = 0; n2_ < 2; ++n2_) {                                        \
        const float* col_ = tb_ + 32 * n2_;                                    \
        short8v bf_;                                                           \
        bf_[0] = bf_rna(col_[0]);   bf_[1] = bf_rna(col_[64]);                 \
        bf_[2] = bf_rna(col_[128]); bf_[3] = bf_rna(col_[192]);                \
        bf_[4] = bf_rna(col_[256]); bf_[5] = bf_rna(col_[320]);                \
        bf_[6] = bf_rna(col_[384]); bf_[7] = bf_rna(col_[448]);                \
        acc[2 * (HF) + n2_] = __builtin_amdgcn_mfma_f32_32x32x16_bf16(         \
            a_, bf_, acc[2 * (HF) + n2_], 0, 0, 0);                            \
    } }

// small per-pixel loads into the "next" register set (13 vmem insts).
#define LOAD_SMALLS(PP) {                                                      \
    const float* W1q_ = W1 + (size_t)(PP) * (DIM_IN * H);                      \
    nb1l  = *reinterpret_cast<const float4*>(b1 + (size_t)(PP) * H + c0);      \
    nb1h  = *reinterpret_cast<const float4*>(b1 + (size_t)(PP) * H + 64 + c0); \
    nw24l = *reinterpret_cast<const float4*>(W1q_ + 24 * H + c0);              \
    nw24h = *reinterpret_cast<const float4*>(W1q_ + 24 * H + 64 + c0);         \
    _Pragma("unroll")                                                          \
    for (int q_ = 0; q_ < 4; ++q_) {                                           \
        nb2v[q_] = b2[(size_t)(PP) * H + 32 * q_ + lo];                        \
        nw3v[q_] = W3[(size_t)(PP) * H + 32 * q_ + lo];                        \
    }                                                                          \
    nb3 = b3[PP]; }

// head+mid of a pixel: expects t0 in buf A, t1 in buf B (already staged),
// smalls in n* registers (already issued, older than t0 in the FIFO).
#define PIX_HEAD(A, B, PCUR)                                                   \
    const float4 b1l = nb1l, b1h = nb1h, w24l = nw24l, w24h = nw24h;           \
    float b2v[4], w3v[4];                                                      \
    _Pragma("unroll")                                                          \
    for (int q_ = 0; q_ < 4; ++q_) { b2v[q_] = nb2v[q_]; w3v[q_] = nw3v[q_]; } \
    const float b3s = nb3;                                                     \
    const float* W1p = W1 + (size_t)(PCUR) * (DIM_IN * H);                     \
    const float* W2p = W2 + (size_t)(PCUR) * (H * H);                          \
    float aL1[8][8];                                                           \
    {                                                                          \
        const float bv[8] = {b1l.x, b1l.y, b1l.z, b1l.w,                       \
                             b1h.x, b1h.y, b1h.z, b1h.w};                      \
        _Pragma("unroll")                                                      \
        for (int i_ = 0; i_ < 8; ++i_)                                         \
            _Pragma("unroll")                                                  \
            for (int c_ = 0; c_ < 8; ++c_)                                     \
                aL1[i_][c_] = bv[c_];                                          \
    }                                                                          \
    asm volatile("s_waitcnt vmcnt(4)" ::: "memory");  /* smalls+t0 done */     \
    L1_CONSUME(A, 0)                                                           \
    asm volatile("s_waitcnt lgkmcnt(0)" ::: "memory");                         \
    STAGE_W1P(A, 2, W1p)                                                       \
    asm volatile("s_waitcnt vmcnt(4)" ::: "memory");  /* t1 done */            \
    L1_CONSUME(B, 1)                                                           \
    asm volatile("s_waitcnt lgkmcnt(0)" ::: "memory");                         \
    STAGE_TP(B, 0, 0, W2p)                                                     \
    asm volatile("s_waitcnt vmcnt(4)" ::: "memory");  /* t2 done */            \
    L1_CONSUME(A, 2)                                                           \
    {   /* row 24 from pre-issued registers */                                 \
        const float4 a0 = *reinterpret_cast<const float4*>(&sxT[24][r0]);      \
        const float4 a1 = *reinterpret_cast<const float4*>(&sxT[24][r0 + 4]);  \
        const float av[8] = {a0.x, a0.y, a0.z, a0.w, a1.x, a1.y, a1.z, a1.w};  \
        const float wv[8] = {w24l.x, w24l.y, w24l.z, w24l.w,                   \
                             w24h.x, w24h.y, w24h.z, w24h.w};                  \
        _Pragma("unroll")                                                      \
        for (int i_ = 0; i_ < 8; ++i_)                                         \
            _Pragma("unroll")                                                  \
            for (int c_ = 0; c_ < 8; ++c_)                                     \
                aL1[i_][c_] += av[i_] * wv[c_];                                \
    }                                                                          \
    asm volatile("s_waitcnt lgkmcnt(0)" ::: "memory");                         \
    STAGE_TP(A, 0, 1, W2p)                                                     \
    _Pragma("unroll")                                                          \
    for (int i_ = 0; i_ < 8; ++i_) {  /* h1 write, XOR-swizzled */             \
        short4v lov, hiv;                                                      \
        lov[0] = bf_rne(leaky(aL1[i_][0])); lov[1] = bf_rne(leaky(aL1[i_][1]));\
        lov[2] = bf_rne(leaky(aL1[i_][2])); lov[3] = bf_rne(leaky(aL1[i_][3]));\
        hiv[0] = bf_rne(leaky(aL1[i_][4])); hiv[1] = bf_rne(leaky(aL1[i_][5]));\
        hiv[2] = bf_rne(leaky(aL1[i_][6])); hiv[3] = bf_rne(leaky(aL1[i_][7]));\
        const int ro_ = (r0 + i_) * 256;                                       \
        const int sz_ = ((r0 + i_) & 7) << 4;                                  \
        *reinterpret_cast<short4v*>((char*)h1b + ((ro_ + 8 * cc) ^ sz_))       = lov; \
        *reinterpret_cast<short4v*>((char*)h1b + ((ro_ + 128 + 8 * cc) ^ sz_)) = hiv; \
    }                                                                          \
    asm volatile("s_waitcnt lgkmcnt(0)" ::: "memory");                         \
    __builtin_amdgcn_sched_barrier(0);                                         \
    f32x16 acc[4];                                                             \
    _Pragma("unroll")                                                          \
    for (int q_ = 0; q_ < 4; ++q_) acc[q_] = (f32x16)(0.f);                    \
    _Pragma("unroll 1")                                                        \
    for (int kt = 0; kt < 7; ++kt) {                                           \
        asm volatile("s_waitcnt vmcnt(4)" ::: "memory");                       \
        CONSUME_T(B, kt, 0)                                                    \
        asm volatile("s_waitcnt lgkmcnt(0)" ::: "memory");                     \
        STAGE_TP(B, kt + 1, 0, W2p)                                            \
        asm volatile("s_waitcnt vmcnt(4)" ::: "memory");                       \
        CONSUME_T(A, kt, 1)                                                    \
        asm volatile("s_waitcnt lgkmcnt(0)" ::: "memory");                     \
        STAGE_TP(A, kt + 1, 1, W2p)                                            \
    }                                                                          \
    asm volatile("s_waitcnt vmcnt(4)" ::: "memory");                           \
    CONSUME_T(B, 7, 0)

// layer-3 + store (uses acc, b2v, w3v, b3s of the current pixel).
#define LAYER3(PCUR) {                                                         \
    float s_[16];                                                              \
    _Pragma("unroll")                                                          \
    for (int rg_ = 0; rg_ < 16; ++rg_) {                                       \
        float a_ = 0.f;                                                        \
        _Pragma("unroll")                                                      \
        for (int q_ = 0; q_ < 4; ++q_)                                         \
            a_ += leaky(acc[q_][rg_] + b2v[q_]) * w3v[q_];                     \
        s_[rg_] = a_;                                                          \
    }                                                                          \
    _Pragma("unroll")                                                          \
    for (int m_ = 16; m_ >= 1; m_ >>= 1) {                                     \
        _Pragma("unroll")                                                      \
        for (int rg_ = 0; rg_ < 16; ++rg_)                                     \
            s_[rg_] += __shfl_xor(s_[rg_], m_);                                \
    }                                                                          \
    if (lo == 0) {                                                             \
        _Pragma("unroll")                                                      \
        for (int rg_ = 0; rg_ < 16; ++rg_) {                                   \
            const int r_ = (rg_ & 3) + 8 * (rg_ >> 2) + 4 * hi;                \
            y[(size_t)r_ * P + (PCUR)] = s_[rg_] + b3s;                        \
        }                                                                      \
    } }

// full pixel with cross-pixel tail: stage next t0'->B, consume T(7,1) from A,
// issue next smalls (FIFO position between t0' and t1'), stage t1'->A.
#define PIX_FULL(A, B, PCUR, PNEXT) {                                          \
    PIX_HEAD(A, B, PCUR)                                                       \
    asm volatile("s_waitcnt lgkmcnt(0)" ::: "memory");                         \
    const float* W1n = W1 + (size_t)(PNEXT) * (DIM_IN * H);                    \
    STAGE_W1P(B, 0, W1n)                                                       \
    asm volatile("s_waitcnt vmcnt(4)" ::: "memory");  /* T(7,1) done */        \
    CONSUME_T(A, 7, 1)                                                         \
    asm volatile("s_waitcnt lgkmcnt(0)" ::: "memory");                         \
    LOAD_SMALLS(PNEXT)                                                         \
    asm volatile("" ::: "memory");                                             \
    STAGE_W1P(A, 1, W1n)                                                       \
    LAYER3(PCUR)                                                               \
    }

// last pixel: drain.
#define PIX_LAST(A, B, PCUR) {                                                 \
    PIX_HEAD(A, B, PCUR)                                                       \
    asm volatile("s_waitcnt vmcnt(0)" ::: "memory");                           \
    CONSUME_T(A, 7, 1)                                                         \
    LAYER3(PCUR)                                                               \
    }

__global__ __launch_bounds__(64, 2) void pixel_mlp_kernel(
    const float* __restrict__ x,    // [BS][DIM_IN]
    const float* __restrict__ W1,   // [P][DIM_IN][H]
    const float* __restrict__ b1,   // [P][H]
    const float* __restrict__ W2,   // [P][H][H]
    const float* __restrict__ b2,   // [P][H]
    const float* __restrict__ W3,   // [P][H]
    const float* __restrict__ b3,   // [P]
    float* __restrict__ y)          // [BS][P]
{
    const int p0 = blockIdx.x * NPIX;
    const int t  = threadIdx.x;     // 0..63, one wave
    const int cc = t & 15;
    const int gg = t >> 4;
    const int c0 = cc << 2;
    const int r0 = gg << 3;
    const int lo = t & 31;
    const int hi = t >> 5;

    __shared__ float sxT[DIM_IN][BS];   // 3.2 KB
    __shared__ short h1b[BS][H];        // 8 KB (reused per pixel)
    __shared__ float w12t[2][16 * 64];  // 8 KB tile double buffer

    float4 nb1l, nb1h, nw24l, nw24h;
    float  nb2v[4], nw3v[4], nb3;

    // x^T staged ONCE, before any DMA (its compiler waits can't drain DMAs)
    for (int i = t; i < DIM_IN * BS; i += 64)
        sxT[i >> 5][i & 31] = x[(i & 31) * DIM_IN + (i >> 5)];
    asm volatile("s_waitcnt vmcnt(0) lgkmcnt(0)" ::: "memory");

    // preamble: pixel p0 smalls (oldest in FIFO), then t0->buf0, t1->buf1
    LOAD_SMALLS(p0)
    asm volatile("" ::: "memory");
    {
        const float* W1q = W1 + (size_t)p0 * (DIM_IN * H);
        STAGE_W1P(0, 0, W1q)
        STAGE_W1P(1, 1, W1q)
    }

    PIX_FULL(0, 1, p0,     p0 + 1)
    PIX_FULL(1, 0, p0 + 1, p0 + 2)
    PIX_FULL(0, 1, p0 + 2, p0 + 3)
    PIX_LAST(1, 0, p0 + 3)
}

extern "C" void kernel_launch(void* const* d_in, const int* in_sizes, int n_in,
                              void* d_out, int out_size, void* d_ws, size_t ws_size,
                              hipStream_t stream) {
    const float* x  = (const float*)d_in[0];
    const float* W1 = (const float*)d_in[1];
    const float* b1 = (const float*)d_in[2];
    const float* W2 = (const float*)d_in[3];
    const float* b2 = (const float*)d_in[4];
    const float* W3 = (const float*)d_in[5];
    const float* b3 = (const float*)d_in[6];
    float* y = (float*)d_out;

    pixel_mlp_kernel<<<dim3(GRID), dim3(64), 0, stream>>>(x, W1, b1, W2, b2, W3, b3, y);
}

// Round 20
// 129.651 us; speedup vs baseline: 1.0545x; 1.0545x over previous
//
#include <hip/hip_runtime.h>

// PerceptronSP: 8000 independent per-pixel MLPs sharing input x.
//   h1 = leaky(x @ W1[p] + b1[p])   [32x25]@[25x128]   f32 VALU
//   h2 = leaky(h1 @ W2[p] + b2[p])  [32x128]@[128x128] bf16 MFMA
//   y[:,p] = h2 @ W3[p] + b3[p]
// ~650 MB streamed once -> ~100 us floor @ 6.6 TB/s (write ref; read ~5 TB/s achieved).
//
// R20 = REVERT to R13 (best, 130.4 us). R19's persistent cross-pixel pipeline
// regressed (136.7): doubled small-reg state + 2000-block grid tail imbalance.
// R13: 8 blocks/CU (2 waves/SIMD). W2 tiles 4 KB [32k x 32n] column-quarters;
// LDS 19.2 KB. 16 tiles/pixel, counted-vmcnt double buffer (vmcnt(4) = oldest
// tile landed, 2 tiles in flight, drain only at tail). Acc index 2*QT+nb, QT
// literal (rule #20).

constexpr int DIM_IN = 25;
constexpr int H      = 128;
constexpr int P      = 8000;
constexpr int BS     = 32;
constexpr float NEG  = 0.01f;

typedef short  short4v __attribute__((ext_vector_type(4)));
typedef short  short8v __attribute__((ext_vector_type(8)));
typedef float  f32x4   __attribute__((ext_vector_type(4)));

__device__ __forceinline__ float leaky(float v) { return v >= 0.f ? v : NEG * v; }

__device__ __forceinline__ short bf_rne(float f) {   // f32 -> bf16 bits, RNE
    unsigned u = __builtin_bit_cast(unsigned, f);
    return (short)((u + 0x7fffu + ((u >> 16) & 1u)) >> 16);
}
__device__ __forceinline__ short bf_rna(float f) {   // f32 -> bf16 bits, round-nearest-away
    unsigned u = __builtin_bit_cast(unsigned, f);
    return (short)((u + 0x8000u) >> 16);
}

// stage one 4KB quarter-tile: W2 rows [32*KT,+32) x cols [32*QT,+32).
// 4 x 1KB DMA insts; inst i covers rows 8i..8i+7 (8 x 128B segments).
// lane l -> row (l>>3), col-quad (l&7); LDS dst wave-uniform + lane*16B
// -> buf is [32][32] f32 row-major.
#define STAGE_Q(BUF, KT, QT) {                                                 \
    const float* gsrc_ = W2p + (size_t)(32 * (KT) + (t >> 3)) * H              \
                         + 32 * (QT) + ((t & 7) << 2);                         \
    float* dst_ = &w2t[BUF][0];                                                \
    _Pragma("unroll")                                                          \
    for (int i_ = 0; i_ < 4; ++i_)                                             \
        __builtin_amdgcn_global_load_lds(                                      \
            (const __attribute__((address_space(1))) unsigned*)(gsrc_ + (size_t)i_ * 8 * H), \
            (__attribute__((address_space(3))) unsigned*)(dst_ + i_ * 256),    \
            16, 0, 0); }

// consume one quarter-tile with K=32 MFMA (R8/R12-verified mapping: lane gg
// owns k = 8*gg + j for BOTH A and B -> any hw K-permutation cancels).
// A-frag: h1b[row=cc][k=32*KT+8*gg+j], one b128 read (+ row 16+cc).
// B-frag: buf[k=8*gg+j][n=16*nb+cc], 8 strided b32 reads + bf16 round.
// QT must be a LITERAL so accumulator indices are compile-time.
#define CONSUME_Q(BUF, KT, QT) {                                               \
    const short8v a0_ = *reinterpret_cast<const short8v*>(                     \
        &h1b[cc][32 * (KT) + 8 * gg]);                                         \
    const short8v a1_ = *reinterpret_cast<const short8v*>(                     \
        &h1b[16 + cc][32 * (KT) + 8 * gg]);                                    \
    const float* tb_ = &w2t[BUF][8 * gg * 32 + cc];                            \
    _Pragma("unroll")                                                          \
    for (int nb_ = 0; nb_ < 2; ++nb_) {                                        \
        const float* col_ = tb_ + 16 * nb_;                                    \
        short8v bf_;                                                           \
        bf_[0] = bf_rna(col_[0 * 32]); bf_[1] = bf_rna(col_[1 * 32]);          \
        bf_[2] = bf_rna(col_[2 * 32]); bf_[3] = bf_rna(col_[3 * 32]);          \
        bf_[4] = bf_rna(col_[4 * 32]); bf_[5] = bf_rna(col_[5 * 32]);          \
        bf_[6] = bf_rna(col_[6 * 32]); bf_[7] = bf_rna(col_[7 * 32]);          \
        ac0[2 * (QT) + nb_] = __builtin_amdgcn_mfma_f32_16x16x32_bf16(         \
            a0_, bf_, ac0[2 * (QT) + nb_], 0, 0, 0);                           \
        ac1[2 * (QT) + nb_] = __builtin_amdgcn_mfma_f32_16x16x32_bf16(         \
            a1_, bf_, ac1[2 * (QT) + nb_], 0, 0, 0);                           \
    } }

// one pipeline step: tile u = 4*kt+qt; buf = qt&1; restage same buf with u+2.
#define QSTEP(KT, QT, NKT, NQT) {                                              \
    asm volatile("s_waitcnt vmcnt(4)" ::: "memory");                           \
    CONSUME_Q((QT) & 1, KT, QT)                                                \
    asm volatile("s_waitcnt lgkmcnt(0)" ::: "memory");                         \
    STAGE_Q((QT) & 1, NKT, NQT) }

__global__ __launch_bounds__(64, 2) void pixel_mlp_kernel(
    const float* __restrict__ x,    // [BS][DIM_IN]
    const float* __restrict__ W1,   // [P][DIM_IN][H]
    const float* __restrict__ b1,   // [P][H]
    const float* __restrict__ W2,   // [P][H][H]
    const float* __restrict__ b2,   // [P][H]
    const float* __restrict__ W3,   // [P][H]
    const float* __restrict__ b3,   // [P]
    float* __restrict__ y)          // [BS][P]
{
    const int p  = blockIdx.x;
    const int t  = threadIdx.x;     // 0..63, one wave
    const int cc = t & 15;          // MFMA n-lane / layer-1 col group
    const int gg = t >> 4;          // MFMA k-group / layer-1 row group
    const int c0 = cc << 2;         // layer-1: first col of low half
    const int r0 = gg << 3;         // layer-1: first row

    __shared__ float sxT[DIM_IN][BS];   // 3.2 KB
    __shared__ short h1b[BS][H];        // 8 KB, h1 as bf16 bits, linear
    __shared__ float w2t[2][32 * 32];   // 8 KB, quarter-tile double buffer

    const float* W1p = W1 + (size_t)p * (DIM_IN * H);
    const float* W2p = W2 + (size_t)p * (H * H);

    // ---- small loads first (oldest in vmcnt FIFO; retire before staging) ----
    const float4 b1l = *reinterpret_cast<const float4*>(b1 + (size_t)p * H + c0);
    const float4 b1h = *reinterpret_cast<const float4*>(b1 + (size_t)p * H + 64 + c0);
    float b2v[8], w3v[8];
    #pragma unroll
    for (int nb = 0; nb < 8; ++nb) {
        b2v[nb] = b2[(size_t)p * H + 16 * nb + cc];
        w3v[nb] = W3[(size_t)p * H + 16 * nb + cc];
    }
    const float b3s = b3[p];
    asm volatile("" ::: "memory");

    // tiles (0,0),(0,1) in flight during layer 1
    STAGE_Q(0, 0, 0)
    STAGE_Q(1, 0, 1)
    asm volatile("" ::: "memory");

    // stage x^T
    for (int i = t; i < DIM_IN * BS; i += 64)
        sxT[i >> 5][i & 31] = x[(i & 31) * DIM_IN + (i >> 5)];
    asm volatile("s_waitcnt lgkmcnt(0)" ::: "memory");

    // ---------------- layer 1: h1 = leaky(x @ W1 + b1), f32 VALU ----------------
    float aL1[8][8];
    {
        const float bv[8] = {b1l.x, b1l.y, b1l.z, b1l.w, b1h.x, b1h.y, b1h.z, b1h.w};
        #pragma unroll
        for (int i = 0; i < 8; ++i)
            #pragma unroll
            for (int c = 0; c < 8; ++c)
                aL1[i][c] = bv[c];
    }
    #pragma unroll 5
    for (int d = 0; d < DIM_IN; ++d) {
        const float4 a0 = *reinterpret_cast<const float4*>(&sxT[d][r0]);
        const float4 a1 = *reinterpret_cast<const float4*>(&sxT[d][r0 + 4]);
        const float av[8] = {a0.x, a0.y, a0.z, a0.w, a1.x, a1.y, a1.z, a1.w};
        const float4 wl = *reinterpret_cast<const float4*>(W1p + d * H + c0);
        const float4 wh = *reinterpret_cast<const float4*>(W1p + d * H + 64 + c0);
        const float wv[8] = {wl.x, wl.y, wl.z, wl.w, wh.x, wh.y, wh.z, wh.w};
        #pragma unroll
        for (int i = 0; i < 8; ++i)
            #pragma unroll
            for (int c = 0; c < 8; ++c)
                aL1[i][c] += av[i] * wv[c];
    }

    // write h1 (leaky, RNE bf16) into the linear [32][128] layout
    #pragma unroll
    for (int i = 0; i < 8; ++i) {
        short4v lo, hi;
        lo[0] = bf_rne(leaky(aL1[i][0])); lo[1] = bf_rne(leaky(aL1[i][1]));
        lo[2] = bf_rne(leaky(aL1[i][2])); lo[3] = bf_rne(leaky(aL1[i][3]));
        hi[0] = bf_rne(leaky(aL1[i][4])); hi[1] = bf_rne(leaky(aL1[i][5]));
        hi[2] = bf_rne(leaky(aL1[i][6])); hi[3] = bf_rne(leaky(aL1[i][7]));
        *reinterpret_cast<short4v*>(&h1b[r0 + i][4 * cc])      = lo;
        *reinterpret_cast<short4v*>(&h1b[r0 + i][64 + 4 * cc]) = hi;
    }
    asm volatile("s_waitcnt lgkmcnt(0)" ::: "memory");
    __builtin_amdgcn_sched_barrier(0);

    // ---------------- layer 2: h2 = leaky(h1 @ W2 + b2), bf16 MFMA ----------------
    f32x4 ac0[8], ac1[8];
    #pragma unroll
    for (int nb = 0; nb < 8; ++nb) {
        ac0[nb] = (f32x4){0.f, 0.f, 0.f, 0.f};
        ac1[nb] = (f32x4){0.f, 0.f, 0.f, 0.f};
    }

    // 16 quarter-tiles (kt 0..3 x qt 0..3); 2 tiles (8 insts) in flight;
    // vmcnt(4) = oldest tile fully landed. Restage stops at tile 15.
    #pragma unroll 1
    for (int kt = 0; kt < 3; ++kt) {
        QSTEP(kt, 0, kt, 2)
        QSTEP(kt, 1, kt, 3)
        QSTEP(kt, 2, kt + 1, 0)
        QSTEP(kt, 3, kt + 1, 1)
    }
    QSTEP(3, 0, 3, 2)
    QSTEP(3, 1, 3, 3)
    asm volatile("s_waitcnt vmcnt(4)" ::: "memory");
    CONSUME_Q(0, 3, 2)
    asm volatile("s_waitcnt vmcnt(0)" ::: "memory");
    CONSUME_Q(1, 3, 3)

    // ---------------- layer 3: y = leaky(h2 + b2) @ W3 + b3 ----------------
    // lane holds D rows b = {4*gg+q, 16+4*gg+q}, col n = 16*nb + cc
    float s0[4], s1[4];
    #pragma unroll
    for (int q = 0; q < 4; ++q) {
        float a = 0.f, b = 0.f;
        #pragma unroll
        for (int nb = 0; nb < 8; ++nb) {
            a += leaky(ac0[nb][q] + b2v[nb]) * w3v[nb];
            b += leaky(ac1[nb][q] + b2v[nb]) * w3v[nb];
        }
        s0[q] = a; s1[q] = b;
    }
    // reduce across the 16 cc lanes
    #pragma unroll
    for (int m = 8; m >= 1; m >>= 1) {
        #pragma unroll
        for (int q = 0; q < 4; ++q) {
            s0[q] += __shfl_xor(s0[q], m);
            s1[q] += __shfl_xor(s1[q], m);
        }
    }
    if (cc == 0) {
        #pragma unroll
        for (int q = 0; q < 4; ++q) {
            y[(size_t)(4 * gg + q) * P + p]      = s0[q] + b3s;
            y[(size_t)(16 + 4 * gg + q) * P + p] = s1[q] + b3s;
        }
    }
}

extern "C" void kernel_launch(void* const* d_in, const int* in_sizes, int n_in,
                              void* d_out, int out_size, void* d_ws, size_t ws_size,
                              hipStream_t stream) {
    const float* x  = (const float*)d_in[0];
    const float* W1 = (const float*)d_in[1];
    const float* b1 = (const float*)d_in[2];
    const float* W2 = (const float*)d_in[3];
    const float* b2 = (const float*)d_in[4];
    const float* W3 = (const float*)d_in[5];
    const float* b3 = (const float*)d_in[6];
    float* y = (float*)d_out;

    pixel_mlp_kernel<<<dim3(P), dim3(64), 0, stream>>>(x, W1, b1, W2, b2, W3, b3, y);
}